// Round 11
// baseline (4577.430 us; speedup 1.0000x reference)
//
#include <hip/hip_runtime.h>
#include <stdint.h>

// Farthest point sampling, pointops semantics.
// B=8 batches, n=65536, stride=64 -> m=1024 samples/batch.
//
// Round 11: wave-granular sync, no barriers in the loop.
// 16 WGs/batch x 4 waves = 64 waves/batch; each wave owns 1024 points
// (LDS float4-transposed) and ONE slot. Per step, a wave:
//   update+argmax (shfl butterfly; all lanes converge) ->
//   lane0 publishes packed key (it|dist|~idx) to sc0 cell (XCD-L2 domain,
//   batch=blockIdx%8 keeps a batch on one XCD) AND sc1 cell (device
//   domain, guaranteed) ->
//   all 64 lanes poll the 64 sc0 slots (8 L2-local lines), BOUNDED, with
//   sticky demotion to unbounded sc1 polling -> shfl key-max -> q-load.
// No __syncthreads in the loop, no LDS reduce/broadcast, no atomics.
//
// Correctness: keys are 8B single-copy-atomic and self-contained; parity-
// double-buffered cells with monotone tags (round-7 induction: a slot's
// parity cell for step it is overwritten only at it+2, which requires its
// wave past poll(it+1), which requires ALL waves published it+1, which
// each does only after completing poll(it) on one of the copies). The sc1
// copy always exists -> bounded sc0 probe can never deadlock (round-10
// scheme, fast path empirically engaged: FETCH 12.6->3.97 MB).
// comm is memset every launch -> graph-replay deterministic.

#define G      16    // workgroups per batch
#define BS     256   // threads per workgroup (4 waves)
#define PPT    16    // points per thread (G*BS*PPT == n)
#define NC     (PPT/4)
#define NBATCH 8
#define NW     64    // waves (= slots) per batch
#define SC0_BUDGET 4096

typedef unsigned long long u64;
typedef unsigned int u32;

// key layout: [63:48]=it  [47:16]=float bits of best dist (nonneg)
//             [15:0]=0xFFFF-idx  (bigger wins => smaller idx wins ties,
//             numpy argmax first-max semantics; nonneg IEEE floats compare
//             like their bit patterns)

__device__ inline u64 ld_sc0(const u64* a) {
    u64 v;
    asm volatile("global_load_dwordx2 %0, %1, off sc0\n\t"
                 "s_waitcnt vmcnt(0)"
                 : "=v"(v) : "v"(a) : "memory");
    return v;
}
__device__ inline void st_sc0(u64* a, u64 v) {
    asm volatile("global_store_dwordx2 %0, %1, off sc0"
                 :: "v"(a), "v"(v) : "memory");
}

__global__ __launch_bounds__(BS, 1)
void fps_wave(const float* __restrict__ p, int n, int m,
              u64* __restrict__ comm,
              float* __restrict__ out_np, float* __restrict__ out_no,
              float* __restrict__ out_idx)
{
#pragma clang fp contract(off)
    const int bg   = blockIdx.x;
    const int b    = bg & (NBATCH - 1);  // %8: co-XCD under round-robin CP
    const int g    = bg >> 3;            // 0..15 within batch
    const int t    = threadIdx.x;
    const int lane = t & 63;
    const int w    = t >> 6;
    const int sid  = g * 4 + w;          // this wave's slot (0..63)
    const int gbase  = b * n;
    const int wgbase = g * (BS * PPT);

    __shared__ float4 xs[NC * BS], ys[NC * BS], zs[NC * BS];   // 48 KB

    // ---- stage coords into LDS (one-time; 12 float4 global loads) ----
    {
        const float4* pb = (const float4*)(p + 3ull * (u32)(gbase + wgbase + t * PPT));
        float c[12 * 4];
#pragma unroll
        for (int v = 0; v < 12; ++v) {
            float4 f = pb[v];
            c[4 * v + 0] = f.x; c[4 * v + 1] = f.y; c[4 * v + 2] = f.z; c[4 * v + 3] = f.w;
        }
#pragma unroll
        for (int cc = 0; cc < NC; ++cc) {
            float4 X, Y, Z;
            X.x = c[(cc * 4 + 0) * 3 + 0]; X.y = c[(cc * 4 + 1) * 3 + 0];
            X.z = c[(cc * 4 + 2) * 3 + 0]; X.w = c[(cc * 4 + 3) * 3 + 0];
            Y.x = c[(cc * 4 + 0) * 3 + 1]; Y.y = c[(cc * 4 + 1) * 3 + 1];
            Y.z = c[(cc * 4 + 2) * 3 + 1]; Y.w = c[(cc * 4 + 3) * 3 + 1];
            Z.x = c[(cc * 4 + 0) * 3 + 2]; Z.y = c[(cc * 4 + 1) * 3 + 2];
            Z.z = c[(cc * 4 + 2) * 3 + 2]; Z.w = c[(cc * 4 + 3) * 3 + 2];
            xs[cc * BS + t] = X; ys[cc * BS + t] = Y; zs[cc * BS + t] = Z;
        }
    }
    __syncthreads();   // LDS ready: the only barrier in the kernel

    float dist[PPT];
#pragma unroll
    for (int j = 0; j < PPT; ++j) dist[j] = 1e10f;

    // first query = point 0 of the batch
    float qx = p[3ull * (u32)gbase + 0];
    float qy = p[3ull * (u32)gbase + 1];
    float qz = p[3ull * (u32)gbase + 2];

    if (g == 0 && t == 0) {
        out_idx[(size_t)b * m] = (float)gbase;
        out_np[(size_t)(b * m) * 3 + 0] = qx;
        out_np[(size_t)(b * m) * 3 + 1] = qy;
        out_np[(size_t)(b * m) * 3 + 2] = qz;
        out_no[b] = (float)((b + 1) * m);
    }

    // per-batch comm (2 KB): parity block = 64 sc0 cells + 64 sc1 cells
    u64* cb = comm + (size_t)b * 256;

    int mode = 0;   // 0 = sc0 (XCD-L2) polling, 1 = sc1 (device) polling

    for (int it = 1; it < m; ++it) {
        // stop LDS values from being promoted/cached across steps
        asm volatile("" ::: "memory");

        // ---- local distance update + per-thread argmax (ids ascend in j) ----
        float best = -1.0f;
        int   bj   = 0;
#pragma unroll
        for (int cc = 0; cc < NC; ++cc) {
            float4 X = xs[cc * BS + t];
            float4 Y = ys[cc * BS + t];
            float4 Z = zs[cc * BS + t];
            float xl[4] = {X.x, X.y, X.z, X.w};
            float yl[4] = {Y.x, Y.y, Y.z, Y.w};
            float zl[4] = {Z.x, Z.y, Z.z, Z.w};
#pragma unroll
            for (int e = 0; e < 4; ++e) {
                float dx = xl[e] - qx;
                float dy = yl[e] - qy;
                float dz = zl[e] - qz;
                float d  = dx * dx + dy * dy + dz * dz;  // contract off: left-assoc
                int j = cc * 4 + e;
                float nd = fminf(dist[j], d);
                dist[j] = nd;
                if (nd > best) { best = nd; bj = j; }    // strict > keeps earliest
            }
        }
        int bidx = wgbase + t * PPT + bj;                // batch-local winner idx

        // ---- wave argmax butterfly (all lanes converge to same result) ----
#pragma unroll
        for (int off = 1; off < 64; off <<= 1) {
            float ov = __shfl_xor(best, off);
            int   oi = __shfl_xor(bidx, off);
            if (ov > best || (ov == best && oi < bidx)) { best = ov; bidx = oi; }
        }

        u64* sb  = cb + (size_t)(it & 1) * 128;   // 64 sc0 cells
        u64* sb1 = sb + NW;                       // 64 sc1 cells

        // ---- lane 0: dual publish of this wave's self-contained key ----
        if (lane == 0) {
            u64 kk = ((u64)(u32)it << 48)
                   | ((u64)(u32)__float_as_uint(best) << 16)
                   | (u64)(u32)(0xFFFF - bidx);
            st_sc0(sb + sid, kk);
            __hip_atomic_store(sb1 + sid, kk, __ATOMIC_RELAXED,
                               __HIP_MEMORY_SCOPE_AGENT);
        }

        // ---- poll: lane i watches slot i; bounded sc0, sticky sc1 demote ----
        u64 k = 0;
        bool done = false;
        if (mode == 0) {
            int tries = 0;
            do {
                k = ld_sc0(sb + lane);   // first iter also drains our stores
                done = __all((u32)(k >> 48) == (u32)it);
            } while (!done && ++tries < SC0_BUDGET);
            if (!done) mode = 1;         // sticky: sc1-only from now on
        }
        if (!done) {
            bool ok;
            do {
                k  = __hip_atomic_load(sb1 + lane, __ATOMIC_RELAXED,
                                       __HIP_MEMORY_SCOPE_AGENT);
                ok = ((u32)(k >> 48) == (u32)it);
            } while (!__all(ok));
        }

        // ---- wave max over 64 keys: (it,dist,-idx) lexicographic ----
#pragma unroll
        for (int off = 1; off < 64; off <<= 1) {
            u64 k2 = __shfl_xor(k, off);
            if (k2 > k) k = k2;
        }
        int kidx = 0xFFFF - (int)(k & 0xFFFF);

        // winner coords from read-only p (L1/L2-warm: loop has no cache-inv)
        const float* wp = p + 3ull * (u32)(gbase + kidx);
        qx = wp[0]; qy = wp[1]; qz = wp[2];

        if (g == 0 && t == 0) {
            out_idx[(size_t)b * m + it] = (float)(gbase + kidx);
            out_np[(size_t)(b * m + it) * 3 + 0] = qx;
            out_np[(size_t)(b * m + it) * 3 + 1] = qy;
            out_np[(size_t)(b * m + it) * 3 + 2] = qz;
        }
    }
}

extern "C" void kernel_launch(void* const* d_in, const int* in_sizes, int n_in,
                              void* d_out, int out_size, void* d_ws, size_t ws_size,
                              hipStream_t stream) {
    const float* p = (const float*)d_in[0];
    int N = in_sizes[0] / 3;           // 524288
    int B = in_sizes[1];               // 8
    int n = N / B;                     // 65536
    int m = (out_size / B - 1) / 4;    // 1024

    float* out_np  = (float*)d_out;
    float* out_no  = out_np + (size_t)B * m * 3;
    float* out_idx = out_no + B;

    u64* comm = (u64*)d_ws;
    // clear all slot cells (both domains, both parities) every launch
    hipMemsetAsync(d_ws, 0, (size_t)NBATCH * 256 * sizeof(u64), stream);

    fps_wave<<<NBATCH * G, BS, 0, stream>>>(p, n, m, comm,
                                            out_np, out_no, out_idx);
}

// Round 12
// 4264.260 us; speedup vs baseline: 1.0734x; 1.0734x over previous
//
#include <hip/hip_runtime.h>
#include <stdint.h>

// Farthest point sampling, pointops semantics.
// B=8 batches, n=65536, stride=64 -> m=1024 samples/batch.
//
// Round 12: lean-step structure. 8 WGs/batch (convoy max-of-8), PPT=32:
// 16 pts/thread in LDS (48 KB) + 16 pts/thread re-streamed from L1/L2 each
// step (loads are q-independent -> overlap compute). Ballot-based wave
// argmax (f32 butterfly + __ballot + __ffsll). ONE __syncthreads per step:
// after the WG candidate is published, EVERY wave polls the single slot
// cacheline itself (8 slots x 8B = 1 line), reduces 8 keys (3 shfl stages),
// and loads q itself -- no second barrier, no LDS broadcast.
//
// Sync scheme (proven rounds 7-11): self-contained packed key
// (it|dist_bits|0xFFFF-idx), parity-double-buffered cells, monotone tags.
// Induction with per-wave readers: publish(it+2) by WG s requires its
// barrier#1(it+2), hence all its waves polled(it+1), which requires every
// WG published(it+1), which (via barrier#1(it+1)) requires all that WG's
// waves completed poll(it) -- i.e. finished reading cell(it). So no reader
// of (it) can observe the (it+2) overwrite, and no deadlock.
// Dual-domain: sc0 copy (XCD-L2, fast; batch=blockIdx%8 co-XCD under
// round-robin CP) + sc1 copy (device scope, guaranteed); bounded sc0 poll
// with sticky demotion to sc1 => deadlock-free even if placement fails.
// comm is memset every launch -> graph-replay deterministic.

#define G      8     // workgroups per batch
#define BS     256   // threads per workgroup (4 waves)
#define PPT    32    // points per thread (G*BS*PPT == n)
#define NCL    4     // LDS chunks (16 pts)
#define NCG    4     // global chunks (16 pts)
#define NBATCH 8
#define SC0_BUDGET 4096

typedef unsigned long long u64;
typedef unsigned int u32;

// key layout: [63:48]=it  [47:16]=float bits of best dist (nonneg)
//             [15:0]=0xFFFF-idx  (bigger wins => smaller idx wins ties,
//             numpy argmax first-max semantics; nonneg IEEE floats compare
//             like their bit patterns)

__device__ inline u64 ld_sc0(const u64* a) {
    u64 v;
    asm volatile("global_load_dwordx2 %0, %1, off sc0\n\t"
                 "s_waitcnt vmcnt(0)"
                 : "=v"(v) : "v"(a) : "memory");
    return v;
}
__device__ inline void st_sc0(u64* a, u64 v) {
    asm volatile("global_store_dwordx2 %0, %1, off sc0"
                 :: "v"(a), "v"(v) : "memory");
}

__global__ __launch_bounds__(BS, 1)
void fps_lean(const float* __restrict__ p, int n, int m,
              u64* __restrict__ comm,
              float* __restrict__ out_np, float* __restrict__ out_no,
              float* __restrict__ out_idx)
{
#pragma clang fp contract(off)
    const int bg   = blockIdx.x;
    const int b    = bg & (NBATCH - 1);  // %8: co-XCD under round-robin CP
    const int g    = bg >> 3;            // 0..7 within batch
    const int t    = threadIdx.x;
    const int lane = t & 63;
    const int w    = t >> 6;
    const int gbase  = b * n;
    const int wgbase = g * (BS * PPT);   // batch-local base of this WG
    const int tbase  = wgbase + t * PPT; // batch-local base of this thread

    __shared__ float4 xs[NCL * BS], ys[NCL * BS], zs[NCL * BS];  // 48 KB
    __shared__ float s_val[BS / 64];
    __shared__ int   s_idx[BS / 64];

    // ---- stage LDS half: points tbase..tbase+15 (12 float4 loads) ----
    {
        const float4* pb = (const float4*)(p + 3ull * (u32)(gbase + tbase));
        float c[12 * 4];
#pragma unroll
        for (int v = 0; v < 12; ++v) {
            float4 f = pb[v];
            c[4 * v + 0] = f.x; c[4 * v + 1] = f.y; c[4 * v + 2] = f.z; c[4 * v + 3] = f.w;
        }
#pragma unroll
        for (int cc = 0; cc < NCL; ++cc) {
            float4 X, Y, Z;
            X.x = c[(cc * 4 + 0) * 3 + 0]; X.y = c[(cc * 4 + 1) * 3 + 0];
            X.z = c[(cc * 4 + 2) * 3 + 0]; X.w = c[(cc * 4 + 3) * 3 + 0];
            Y.x = c[(cc * 4 + 0) * 3 + 1]; Y.y = c[(cc * 4 + 1) * 3 + 1];
            Y.z = c[(cc * 4 + 2) * 3 + 1]; Y.w = c[(cc * 4 + 3) * 3 + 1];
            Z.x = c[(cc * 4 + 0) * 3 + 2]; Z.y = c[(cc * 4 + 1) * 3 + 2];
            Z.z = c[(cc * 4 + 2) * 3 + 2]; Z.w = c[(cc * 4 + 3) * 3 + 2];
            xs[cc * BS + t] = X; ys[cc * BS + t] = Y; zs[cc * BS + t] = Z;
        }
    }
    __syncthreads();

    float dist[PPT];
#pragma unroll
    for (int j = 0; j < PPT; ++j) dist[j] = 1e10f;

    // first query = point 0 of the batch
    float qx = p[3ull * (u32)gbase + 0];
    float qy = p[3ull * (u32)gbase + 1];
    float qz = p[3ull * (u32)gbase + 2];

    if (g == 0 && t == 0) {
        out_idx[(size_t)b * m] = (float)gbase;
        out_np[(size_t)(b * m) * 3 + 0] = qx;
        out_np[(size_t)(b * m) * 3 + 1] = qy;
        out_np[(size_t)(b * m) * 3 + 2] = qz;
        out_no[b] = (float)((b + 1) * m);
    }

    // per-batch comm (512 B): line0 = sc0 par0, line1 = sc0 par1,
    //                         line2 = sc1 par0, line3 = sc1 par1
    u64* cb = comm + (size_t)b * 64;

    int mode = 0;   // 0 = sc0 (XCD-L2) polling, 1 = sc1 (device) polling

    for (int it = 1; it < m; ++it) {
        // prevent cross-iteration promotion/caching of LDS & global reads
        asm volatile("" ::: "memory");

        float best = -1.0f;
        int   bj   = 0;

        // ---- LDS half: j = 0..15 ----
#pragma unroll
        for (int cc = 0; cc < NCL; ++cc) {
            float4 X = xs[cc * BS + t];
            float4 Y = ys[cc * BS + t];
            float4 Z = zs[cc * BS + t];
            float xl[4] = {X.x, X.y, X.z, X.w};
            float yl[4] = {Y.x, Y.y, Y.z, Y.w};
            float zl[4] = {Z.x, Z.y, Z.z, Z.w};
#pragma unroll
            for (int e = 0; e < 4; ++e) {
                float dx = xl[e] - qx;
                float dy = yl[e] - qy;
                float dz = zl[e] - qz;
                float d  = dx * dx + dy * dy + dz * dz;  // contract off
                int j = cc * 4 + e;
                float nd = fminf(dist[j], d);
                dist[j] = nd;
                if (nd > best) { best = nd; bj = j; }    // strict > keeps earliest
            }
        }

        // ---- global half: j = 16..31 (q-independent loads, overlap) ----
#pragma unroll
        for (int cc = 0; cc < NCG; ++cc) {
            const float4* gp =
                (const float4*)(p + 3ull * (u32)(gbase + tbase + 16 + cc * 4));
            float4 f0 = gp[0], f1 = gp[1], f2 = gp[2];
            float cf[12] = {f0.x, f0.y, f0.z, f0.w,
                            f1.x, f1.y, f1.z, f1.w,
                            f2.x, f2.y, f2.z, f2.w};
#pragma unroll
            for (int e = 0; e < 4; ++e) {
                float dx = cf[3 * e + 0] - qx;
                float dy = cf[3 * e + 1] - qy;
                float dz = cf[3 * e + 2] - qz;
                float d  = dx * dx + dy * dy + dz * dz;  // contract off
                int j = 16 + cc * 4 + e;
                float nd = fminf(dist[j], d);
                dist[j] = nd;
                if (nd > best) { best = nd; bj = j; }
            }
        }
        int bidx = tbase + bj;   // batch-local winner idx (ascends with lane)

        // ---- ballot wave argmax: max butterfly + first-max lane pick ----
        float v = best;
#pragma unroll
        for (int off = 1; off < 64; off <<= 1)
            v = fmaxf(v, __shfl_xor(v, off));
        u64 msk = __ballot(best == v);
        int src = __ffsll((unsigned long long)msk) - 1;
        int widx = __shfl(bidx, src);    // smallest idx among maxima

        if (lane == 0) { s_val[w] = v; s_idx[w] = widx; }
        __syncthreads();                 // the only barrier per step

        u64* sb0 = cb + (size_t)(it & 1) * 8;        // sc0 cells (1 line)
        u64* sb1 = cb + 16 + (size_t)(it & 1) * 8;   // sc1 cells (1 line)

        // ---- t0: WG reduce (4 entries) + dual publish ----
        if (t == 0) {
            float vv = -1.0f; int ix = 0x7fffffff;
#pragma unroll
            for (int ww = 0; ww < BS / 64; ++ww) {
                if (s_val[ww] > vv || (s_val[ww] == vv && s_idx[ww] < ix)) {
                    vv = s_val[ww]; ix = s_idx[ww];
                }
            }
            u64 kk = ((u64)(u32)it << 48)
                   | ((u64)(u32)__float_as_uint(vv) << 16)
                   | (u64)(u32)(0xFFFF - ix);
            st_sc0(sb0 + g, kk);
            __hip_atomic_store(sb1 + g, kk, __ATOMIC_RELAXED,
                               __HIP_MEMORY_SCOPE_AGENT);
        }

        // ---- EVERY wave: poll the slot line; bounded sc0, sticky sc1 ----
        u64 k = 0;
        bool done = false;
        if (mode == 0) {
            int tries = 0;
            do {
                bool ok = true;
                if (lane < G) {
                    k  = ld_sc0(sb0 + lane);
                    ok = ((u32)(k >> 48) == (u32)it);
                }
                done = __all(ok);
            } while (!done && ++tries < SC0_BUDGET);
            if (!done) mode = 1;         // sticky: sc1-only from now on
        }
        if (!done) {
            bool ok;
            do {
                ok = true;
                if (lane < G) {
                    k  = __hip_atomic_load(sb1 + lane, __ATOMIC_RELAXED,
                                           __HIP_MEMORY_SCOPE_AGENT);
                    ok = ((u32)(k >> 48) == (u32)it);
                }
            } while (!__all(ok));
        }

        // ---- max over 8 keys (3 stages, lanes 0..7), broadcast ----
#pragma unroll
        for (int off = 1; off < G; off <<= 1) {
            u64 k2 = __shfl_xor(k, off);
            if (k2 > k) k = k2;
        }
        int kidx = 0xFFFF - (int)(k & 0xFFFF);
        kidx = __shfl(kidx, 0);

        // winner coords from read-only p (L1/L2-warm: loop has no cache-inv)
        const float* wp = p + 3ull * (u32)(gbase + kidx);
        qx = wp[0]; qy = wp[1]; qz = wp[2];

        if (g == 0 && t == 0) {
            out_idx[(size_t)b * m + it] = (float)(gbase + kidx);
            out_np[(size_t)(b * m + it) * 3 + 0] = qx;
            out_np[(size_t)(b * m + it) * 3 + 1] = qy;
            out_np[(size_t)(b * m + it) * 3 + 2] = qz;
        }
    }
}

extern "C" void kernel_launch(void* const* d_in, const int* in_sizes, int n_in,
                              void* d_out, int out_size, void* d_ws, size_t ws_size,
                              hipStream_t stream) {
    const float* p = (const float*)d_in[0];
    int N = in_sizes[0] / 3;           // 524288
    int B = in_sizes[1];               // 8
    int n = N / B;                     // 65536
    int m = (out_size / B - 1) / 4;    // 1024

    float* out_np  = (float*)d_out;
    float* out_no  = out_np + (size_t)B * m * 3;
    float* out_idx = out_no + B;

    u64* comm = (u64*)d_ws;
    // clear all slot cells (both domains, both parities) every launch
    hipMemsetAsync(d_ws, 0, (size_t)NBATCH * 64 * sizeof(u64), stream);

    fps_lean<<<NBATCH * G, BS, 0, stream>>>(p, n, m, comm,
                                            out_np, out_no, out_idx);
}

// Round 13
// 2153.021 us; speedup vs baseline: 2.1260x; 1.9806x over previous
//
#include <hip/hip_runtime.h>
#include <stdint.h>

// Farthest point sampling, pointops semantics.
// B=8 batches, n=65536, stride=64 -> m=1024 samples/batch.
//
// Round 13: 1-wave workgroups -- the wave IS the workgroup.
// 32 WGs/batch x 64 threads x 32 pts/thread (all in LDS, 24 KB/WG).
// ZERO __syncthreads in the loop, no intra-WG reduce, no convoy.
// Per step, each wave: dist update (LDS float4) -> ballot argmax ->
// lane0 dual-publishes packed key (sc0 cell: XCD-L2 domain, batch =
// blockIdx%8 co-XCD under round-robin CP; sc1 cell: device domain,
// guaranteed) -> all lanes DUAL-PROBE poll (sc0 first, sc1 fallback,
// EVERY iteration -- no budget, no sticky state: immune to round-11's
// demotion poisoning, deadlock-free since the sc1 probe always
// eventually observes the tag) -> 6-stage u64 key-max butterfly (upper
// 32 lanes hold key 0, never win; result in all lanes) -> q-load.
//
// Correctness: keys are 8B single-copy-atomic, self-contained
// (it|dist_bits|0xFFFF-idx); parity-double-buffered cells, monotone
// tags; round-7 induction: slot s's parity cell for step it is
// overwritten only by publish(it+2) from wave s, which follows wave s's
// poll(it+1), which requires EVERY wave published (it+1), which each
// does only after completing poll(it) in wave program order. Both
// copies carry identical payloads -> result independent of which copy
// satisfied the probe. comm memset every launch -> replay-deterministic.

#define G      32    // workgroups (waves) per batch
#define BS     64    // threads per workgroup = 1 wave
#define PPT    32    // points per thread (G*BS*PPT == n)
#define NC     8     // float4 chunks per thread
#define NBATCH 8

typedef unsigned long long u64;
typedef unsigned int u32;

// key layout: [63:48]=it  [47:16]=float bits of best dist (nonneg)
//             [15:0]=0xFFFF-idx  (bigger wins => smaller idx wins ties,
//             numpy argmax first-max semantics; nonneg IEEE floats
//             compare like their bit patterns)

__device__ inline u64 ld_sc0(const u64* a) {
    u64 v;
    asm volatile("global_load_dwordx2 %0, %1, off sc0\n\t"
                 "s_waitcnt vmcnt(0)"
                 : "=v"(v) : "v"(a) : "memory");
    return v;
}
__device__ inline void st_sc0(u64* a, u64 v) {
    asm volatile("global_store_dwordx2 %0, %1, off sc0"
                 :: "v"(a), "v"(v) : "memory");
}

__global__ __launch_bounds__(BS, 1)
void fps_1w(const float* __restrict__ p, int n, int m,
            u64* __restrict__ comm,
            float* __restrict__ out_np, float* __restrict__ out_no,
            float* __restrict__ out_idx)
{
#pragma clang fp contract(off)
    const int bg   = blockIdx.x;
    const int b    = bg & (NBATCH - 1);  // %8: co-XCD under round-robin CP
    const int g    = bg >> 3;            // 0..31 within batch
    const int t    = threadIdx.x;        // == lane
    const int gbase = b * n;
    const int tbase = g * (BS * PPT) + t * PPT;  // batch-local thread base

    __shared__ float4 xs[NC * BS], ys[NC * BS], zs[NC * BS];  // 24 KB

    // ---- stage 32 pts/thread into LDS (two halves, low reg pressure) ----
    {
        const float4* pb = (const float4*)(p + 3ull * (u32)(gbase + tbase));
#pragma unroll
        for (int h = 0; h < 2; ++h) {
            float c[48];
#pragma unroll
            for (int v = 0; v < 12; ++v) {
                float4 f = pb[h * 12 + v];
                c[4 * v + 0] = f.x; c[4 * v + 1] = f.y;
                c[4 * v + 2] = f.z; c[4 * v + 3] = f.w;
            }
#pragma unroll
            for (int cc = 0; cc < 4; ++cc) {
                int ch = h * 4 + cc;
                xs[ch * BS + t] = make_float4(c[(cc * 4 + 0) * 3 + 0],
                                              c[(cc * 4 + 1) * 3 + 0],
                                              c[(cc * 4 + 2) * 3 + 0],
                                              c[(cc * 4 + 3) * 3 + 0]);
                ys[ch * BS + t] = make_float4(c[(cc * 4 + 0) * 3 + 1],
                                              c[(cc * 4 + 1) * 3 + 1],
                                              c[(cc * 4 + 2) * 3 + 1],
                                              c[(cc * 4 + 3) * 3 + 1]);
                zs[ch * BS + t] = make_float4(c[(cc * 4 + 0) * 3 + 2],
                                              c[(cc * 4 + 1) * 3 + 2],
                                              c[(cc * 4 + 2) * 3 + 2],
                                              c[(cc * 4 + 3) * 3 + 2]);
            }
        }
    }
    __syncthreads();   // single-wave WG: trivial; LDS ready

    float dist[PPT];
#pragma unroll
    for (int j = 0; j < PPT; ++j) dist[j] = 1e10f;

    // first query = point 0 of the batch
    float qx = p[3ull * (u32)gbase + 0];
    float qy = p[3ull * (u32)gbase + 1];
    float qz = p[3ull * (u32)gbase + 2];

    if (g == 0 && t == 0) {
        out_idx[(size_t)b * m] = (float)gbase;
        out_np[(size_t)(b * m) * 3 + 0] = qx;
        out_np[(size_t)(b * m) * 3 + 1] = qy;
        out_np[(size_t)(b * m) * 3 + 2] = qz;
        out_no[b] = (float)((b + 1) * m);
    }

    // per-batch comm (1 KB): sc0 cells [par*32], sc1 cells [64 + par*32]
    u64* cb = comm + (size_t)b * 128;

    for (int it = 1; it < m; ++it) {
        // prevent cross-iteration promotion/caching of LDS reads
        asm volatile("" ::: "memory");

        // ---- local distance update + per-thread argmax (ids ascend in j) ----
        float best = -1.0f;
        int   bj   = 0;
#pragma unroll
        for (int cc = 0; cc < NC; ++cc) {
            float4 X = xs[cc * BS + t];
            float4 Y = ys[cc * BS + t];
            float4 Z = zs[cc * BS + t];
            float xl[4] = {X.x, X.y, X.z, X.w};
            float yl[4] = {Y.x, Y.y, Y.z, Y.w};
            float zl[4] = {Z.x, Z.y, Z.z, Z.w};
#pragma unroll
            for (int e = 0; e < 4; ++e) {
                float dx = xl[e] - qx;
                float dy = yl[e] - qy;
                float dz = zl[e] - qz;
                float d  = dx * dx + dy * dy + dz * dz;  // contract off
                int j = cc * 4 + e;
                float nd = fminf(dist[j], d);
                dist[j] = nd;
                if (nd > best) { best = nd; bj = j; }    // strict >: earliest j
            }
        }
        int bidx = tbase + bj;   // batch-local winner idx (ascends with lane)

        // ---- ballot wave argmax: max butterfly + first-max lane pick ----
        float v = best;
#pragma unroll
        for (int off = 1; off < 64; off <<= 1)
            v = fmaxf(v, __shfl_xor(v, off));
        u64 msk = __ballot(best == v);
        int src = __ffsll((unsigned long long)msk) - 1;
        int widx = __shfl(bidx, src);    // smallest idx among maxima

        u64* sb0 = cb + (size_t)(it & 1) * G;        // sc0 cells (2 lines)
        u64* sb1 = cb + 2 * G + (size_t)(it & 1) * G; // sc1 cells (2 lines)

        // ---- lane 0: dual publish of this wave's self-contained key ----
        if (t == 0) {
            u64 kk = ((u64)(u32)it << 48)
                   | ((u64)(u32)__float_as_uint(v) << 16)
                   | (u64)(u32)(0xFFFF - widx);
            st_sc0(sb0 + g, kk);
            __hip_atomic_store(sb1 + g, kk, __ATOMIC_RELAXED,
                               __HIP_MEMORY_SCOPE_AGENT);
        }

        // ---- all lanes: dual-probe poll (sc0 fast, sc1 guaranteed) ----
        u64 k = 0;
        bool ok;
        do {
            ok = true;
            if (t < G) {
                k = ld_sc0(sb0 + t);
                if ((u32)(k >> 48) != (u32)it) {
                    k = __hip_atomic_load(sb1 + t, __ATOMIC_RELAXED,
                                          __HIP_MEMORY_SCOPE_AGENT);
                }
                ok = ((u32)(k >> 48) == (u32)it);
            } else {
                k = 0;   // upper lanes: never win the key-max
            }
        } while (!__all(ok));

        // ---- key-max butterfly over 64 lanes (upper 32 carry 0) ----
#pragma unroll
        for (int off = 1; off < 64; off <<= 1) {
            u64 k2 = __shfl_xor(k, off);
            if (k2 > k) k = k2;
        }
        int kidx = 0xFFFF - (int)(k & 0xFFFF);

        // winner coords from read-only p (L1/L2-warm; no cache-inv in loop)
        const float* wp = p + 3ull * (u32)(gbase + kidx);
        qx = wp[0]; qy = wp[1]; qz = wp[2];

        if (g == 0 && t == 0) {
            out_idx[(size_t)b * m + it] = (float)(gbase + kidx);
            out_np[(size_t)(b * m + it) * 3 + 0] = qx;
            out_np[(size_t)(b * m + it) * 3 + 1] = qy;
            out_np[(size_t)(b * m + it) * 3 + 2] = qz;
        }
    }
}

extern "C" void kernel_launch(void* const* d_in, const int* in_sizes, int n_in,
                              void* d_out, int out_size, void* d_ws, size_t ws_size,
                              hipStream_t stream) {
    const float* p = (const float*)d_in[0];
    int N = in_sizes[0] / 3;           // 524288
    int B = in_sizes[1];               // 8
    int n = N / B;                     // 65536
    int m = (out_size / B - 1) / 4;    // 1024

    float* out_np  = (float*)d_out;
    float* out_no  = out_np + (size_t)B * m * 3;
    float* out_idx = out_no + B;

    u64* comm = (u64*)d_ws;
    // clear all slot cells (both domains, both parities) every launch
    hipMemsetAsync(d_ws, 0, (size_t)NBATCH * 128 * sizeof(u64), stream);

    fps_1w<<<NBATCH * G, BS, 0, stream>>>(p, n, m, comm,
                                          out_np, out_no, out_idx);
}